// Round 5
// baseline (373.171 us; speedup 1.0000x reference)
//
#include <hip/hip_runtime.h>
#include <hip/hip_bf16.h>
#include <stdint.h>

typedef unsigned short u16;
typedef unsigned int u32;
typedef unsigned long long u64;
typedef __bf16 bf16x8 __attribute__((ext_vector_type(8)));
typedef _Float16 f16x8 __attribute__((ext_vector_type(8)));
typedef float f32x4 __attribute__((ext_vector_type(4)));

#define M_ROWS 32768   // bs*seq
#define DIM    1024    // inp_dim
#define NPROJ  64
#define NBINS  20
#define FDIM   1280    // NPROJ*NBINS
#define EDIM   1024    // emb_dim

// round-to-nearest-even f32 -> bf16 (no NaNs in this problem)
__device__ __forceinline__ u16 f2bf(float f) {
    union { float f; u32 u; } v; v.f = f;
    return (u16)((v.u + 0x7FFFu + ((v.u >> 16) & 1u)) >> 16);
}

__device__ __forceinline__ float wave_sum(float v) {
    #pragma unroll
    for (int o = 32; o > 0; o >>= 1) v += __shfl_down(v, o, 64);
    return v;
}

__device__ __forceinline__ void gl_lds16(const void* g, void* l) {
    __builtin_amdgcn_global_load_lds(
        (const __attribute__((address_space(1))) void*)g,
        (__attribute__((address_space(3))) void*)l, 16, 0, 0);
}

__device__ __forceinline__ f32x4 mfma16(f16x8 a, f16x8 b, f32x4 c) {
    return __builtin_amdgcn_mfma_f32_16x16x32_f16(a, b, c, 0, 0, 0);
}

// scaled f16 split: f = hi + lo*2^-12, lo kept in normal f16 range.
__device__ __forceinline__ void split8(const float* f, f16x8& hi, f16x8& lo) {
    #pragma unroll
    for (int e = 0; e < 8; e++) {
        _Float16 h = (_Float16)f[e];
        hi[e] = h;
        lo[e] = (_Float16)((f[e] - (float)h) * 4096.0f);
    }
}

// ---------------------------------------------------------------------------
// K1 v2: normalize proj_weight rows, split to f16 hi / scaled-lo, and store
// LANE-MAJOR fragment images for direct register B-loads in k_fused:
//   img[(s*8 + ks*4 + jf)*512 + lane*8 + e]  (u16 units)
// where lane = q*16 + m16, proj P = jf*16+m16, k = s*64 + ks*32 + q*8 + e.
// A wave's fragment load (fixed s,ks,jf) is then 64 lanes x 16B contiguous
// = perfectly coalesced 1KB, no LDS, no swizzle needed.
// 64 blocks x 256 threads (one block per proj row P, thread t -> k=4t..4t+3;
// those 4 share (s,ks,q) and e0=(4t)&7 in {0,4} -> one aligned u64 store).
__global__ void k_norm_w(const float* __restrict__ w, u16* __restrict__ wswh,
                         u16* __restrict__ wswl) {
    int P = blockIdx.x;
    int t = threadIdx.x;
    float4 v = ((const float4*)(w + (size_t)P * DIM))[t];
    float ss = v.x*v.x + v.y*v.y + v.z*v.z + v.w*v.w;
    ss = wave_sum(ss);
    __shared__ float red[4];
    if ((t & 63) == 0) red[t >> 6] = ss;
    __syncthreads();
    float rn = 1.0f / fmaxf(sqrtf(red[0] + red[1] + red[2] + red[3]), 1e-12f);
    float wn[4] = {v.x*rn, v.y*rn, v.z*rn, v.w*rn};
    u64 hp = 0, lp = 0;
    #pragma unroll
    for (int e = 0; e < 4; e++) {
        _Float16 h = (_Float16)wn[e];
        _Float16 l = (_Float16)((wn[e] - (float)h) * 4096.0f);
        union { _Float16 f; u16 u; } ch, cl;
        ch.f = h; cl.f = l;
        hp |= (u64)ch.u << (16 * e);
        lp |= (u64)cl.u << (16 * e);
    }
    int k0 = 4 * t;
    int s  = k0 >> 6, ks = (k0 >> 5) & 1, q = (k0 >> 3) & 3, e0 = k0 & 7;
    int lane = q * 16 + (P & 15);
    int jf = P >> 4;
    int idx = (s * 8 + ks * 4 + jf) * 512 + lane * 8 + e0;   // u16 units, 8B-aligned
    *(u64*)(wswh + idx) = hp;
    *(u64*)(wswl + idx) = lp;
}

// ---------------------------------------------------------------------------
// K3: emb_weight fp32 -> bf16, same [EDIM][FDIM] layout. 1280 blocks.
__global__ void k_cvt(const float* __restrict__ s, u16* __restrict__ d) {
    int i = blockIdx.x * 256 + threadIdx.x;
    float4 v = ((const float4*)s)[i];
    ushort4 o; o.x = f2bf(v.x); o.y = f2bf(v.y); o.z = f2bf(v.z); o.w = f2bf(v.w);
    ((ushort4*)d)[i] = o;
}

// ---------------------------------------------------------------------------
// K_FUSED v3: barrier-free GEMM1 + in-register act.
// - B fragments loaded straight from L2-resident lane-major images (no LDS,
//   no double-buffer, no per-step barrier -> waves independent, compiler
//   pipelines loads across steps). x prefetched one step ahead in regs.
// - MFMA C-layout keeps p lane-local: lane (m16,q) holds p for rows wm+q*4+r,
//   projs j*16+m16 -> act runs on own accumulators, no pl redistribution.
// - rn via xor-reduce + broadcast shfl. Single __syncthreads (means table).
// Arithmetic is op-for-op identical to v2 -> bit-identical z.
__global__ __launch_bounds__(256) void k_fused(const float* __restrict__ x,
        const u16* __restrict__ wswh, const u16* __restrict__ wswl,
        const float* __restrict__ mean, u16* __restrict__ z) {
    __shared__ float mlds[64 * 21];  // mean, stride 21 (16 distinct banks)
    int t = threadIdx.x;
    int lane = t & 63, wave = t >> 6;
    int m16 = lane & 15, q = lane >> 4;
    int bm = blockIdx.x * 64;
    int wm = wave * 16;
    const float* xr = x + (size_t)(bm + wm + m16) * DIM;   // this lane's A row

    // stage means (consumed after the one barrier below)
    for (int i = t; i < 64 * 21; i += 256) {
        int j = i / 21, b = i - j * 21;
        if (b < 20) mlds[i] = mean[j * 20 + b];
    }

    f32x4 accA[4], accB[4];
    #pragma unroll
    for (int j = 0; j < 4; j++) { accA[j] = (f32x4){0,0,0,0}; accB[j] = (f32x4){0,0,0,0}; }
    float ssl = 0.f;

    // x(0) prefetch
    float4 c0 = *(const float4*)(xr + q * 8);
    float4 c1 = *(const float4*)(xr + q * 8 + 4);
    float4 c2 = *(const float4*)(xr + q * 8 + 32);
    float4 c3 = *(const float4*)(xr + q * 8 + 36);

    const u16* whb = wswh + lane * 8;
    const u16* wlb = wswl + lane * 8;

    #pragma unroll 2
    for (int s = 0; s < 16; s++) {
        float4 n0, n1, n2, n3;
        if (s < 15) {
            const float* xn = xr + (s + 1) * 64 + q * 8;
            n0 = *(const float4*)(xn);
            n1 = *(const float4*)(xn + 4);
            n2 = *(const float4*)(xn + 32);
            n3 = *(const float4*)(xn + 36);
        }

        ssl += c0.x*c0.x + c0.y*c0.y + c0.z*c0.z + c0.w*c0.w;
        ssl += c1.x*c1.x + c1.y*c1.y + c1.z*c1.z + c1.w*c1.w;
        ssl += c2.x*c2.x + c2.y*c2.y + c2.z*c2.z + c2.w*c2.w;
        ssl += c3.x*c3.x + c3.y*c3.y + c3.z*c3.z + c3.w*c3.w;

        float av0[8] = {c0.x, c0.y, c0.z, c0.w, c1.x, c1.y, c1.z, c1.w};
        float av1[8] = {c2.x, c2.y, c2.z, c2.w, c3.x, c3.y, c3.z, c3.w};
        f16x8 ah[2], al[2];
        split8(av0, ah[0], al[0]);
        split8(av1, ah[1], al[1]);

        #pragma unroll
        for (int ks = 0; ks < 2; ks++) {
            #pragma unroll
            for (int j = 0; j < 4; j++) {
                int fo = (s * 8 + ks * 4 + j) * 512;     // u16 units
                f16x8 bh = *(const f16x8*)(whb + fo);    // coalesced 16B/lane, L2-hit
                f16x8 bl = *(const f16x8*)(wlb + fo);
                accA[j] = mfma16(ah[ks], bh, accA[j]);
                accB[j] = mfma16(ah[ks], bl, accB[j]);
                accB[j] = mfma16(al[ks], bh, accB[j]);
            }
        }
        c0 = n0; c1 = n1; c2 = n2; c3 = n3;
    }

    // --- rn: 4 q-lanes of a row hold disjoint partials; reduce then broadcast
    ssl += __shfl_xor(ssl, 16, 64);
    ssl += __shfl_xor(ssl, 32, 64);
    float rn_own = 1.0f / fmaxf(sqrtf(ssl), 1e-12f);   // for row (wm+)m16
    float rnr[4];
    #pragma unroll
    for (int r = 0; r < 4; r++) rnr[r] = __shfl(rn_own, q * 4 + r, 64);

    __syncthreads();   // means staged

    // --- act fully in-register: 16 (j,r) groups per lane
    #pragma unroll 1
    for (int j = 0; j < 4; j++) {
        int P = j * 16 + m16;
        const float* mj = &mlds[P * 21];
        float mv[NBINS];
        #pragma unroll
        for (int b = 0; b < NBINS; b++) mv[b] = mj[b];
        #pragma unroll 1
        for (int r = 0; r < 4; r++) {
            float pv = (accA[j][r] + accB[j][r] * 2.44140625e-4f) * rnr[r];
            float act[NBINS];
            float top0 = -1e30f, top1 = -1e30f, top2 = -1e30f, top3 = -1e30f;
            #pragma unroll
            for (int b = 0; b < NBINS; b++) {
                float d = pv - mv[b];
                float a = __expf(-50.0f * d * d);   // 0.5/sigma2 = 50
                act[b] = a;
                if (a > top3) {
                    if (a > top0)      { top3 = top2; top2 = top1; top1 = top0; top0 = a; }
                    else if (a > top1) { top3 = top2; top2 = top1; top1 = a; }
                    else if (a > top2) { top3 = top2; top2 = a; }
                    else               { top3 = a; }
                }
            }
            float ss = 0.f;
            #pragma unroll
            for (int b = 0; b < NBINS; b++) {
                float a = (act[b] >= top3) ? act[b] : 0.0f;   // keep ties
                act[b] = a;
                ss += a * a;
            }
            float rr = 1.0f / fmaxf(sqrtf(ss), 1e-12f);
            u64 pk[5];
            #pragma unroll
            for (int i2 = 0; i2 < 5; i2++) {
                u64 w0 = f2bf(act[4*i2]     * rr);
                u64 w1 = f2bf(act[4*i2 + 1] * rr);
                u64 w2 = f2bf(act[4*i2 + 2] * rr);
                u64 w3 = f2bf(act[4*i2 + 3] * rr);
                pk[i2] = w0 | (w1 << 16) | (w2 << 32) | (w3 << 48);
            }
            int row = bm + wm + q * 4 + r;
            u64* zp = (u64*)(z + ((size_t)row * FDIM + P * NBINS));  // 40B, 8B-aligned
            #pragma unroll
            for (int i2 = 0; i2 < 5; i2++) zp[i2] = pk[i2];
        }
    }
}

// ---------------------------------------------------------------------------
// K6 v3 (unchanged): GEMM2 bf16 MFMA, BK=64 single-buffer 2-barrier,
// G21 both-sides granule swizzle (conflict-free), XCD-swizzled grid.
__global__ __launch_bounds__(256) void k_gemm2(const u16* __restrict__ A,
                                               const u16* __restrict__ B,
                                               float* __restrict__ C) {
    const int K = FDIM, N = EDIM;
    __shared__ u16 As[128 * 64];   // 16KB, [row][64k] granule-swizzled
    __shared__ u16 Bs[128 * 64];   // 16KB
    int t = threadIdx.x;
    int lane = t & 63, wave = t >> 6;
    int sfl  = (blockIdx.y << 3) | blockIdx.x;        // hw dispatch order (x fastest)
    int tile = ((sfl & 7) << 8) | (sfl >> 3);         // xcd*256 + idx-in-xcd
    int bm = (tile >> 3) * 128;                       // 0..255 M-tiles
    int bn = (tile & 7) * 128;                        // 0..7   N-tiles
    int wm = (wave >> 1) * 64, wn = (wave & 1) * 64;
    int m16 = lane & 15, q = lane >> 4;

    f32x4 zero = {0.f, 0.f, 0.f, 0.f};
    f32x4 acc[4][4];
    #pragma unroll
    for (int i = 0; i < 4; i++)
        #pragma unroll
        for (int j = 0; j < 4; j++) acc[i][j] = zero;

    int srow = t >> 3;                  // 0..31
    int gsw  = (t & 7) ^ (srow & 7);    // swizzled source granule
    const u16* gA = A + (size_t)(bm + srow) * K + gsw * 8;
    const u16* gB = B + (size_t)(bn + srow) * K + gsw * 8;
    u16* la = &As[t * 8];
    u16* lb = &Bs[t * 8];

    int swz = (m16 & 7) << 3;

    for (int tt = 0; tt < 20; tt++) {
        int k0 = tt * 64;
        #pragma unroll
        for (int r = 0; r < 4; r++) {
            gl_lds16(gA + (size_t)(32 * r) * K + k0, la + r * 2048);
            gl_lds16(gB + (size_t)(32 * r) * K + k0, lb + r * 2048);
        }
        __syncthreads();
        #pragma unroll
        for (int ks = 0; ks < 2; ks++) {
            bf16x8 af[4], bfr[4];
            #pragma unroll
            for (int i = 0; i < 4; i++)
                af[i] = *(const bf16x8*)&As[(wm + i * 16 + m16) * 64 + ((ks * 32 + q * 8) ^ swz)];
            #pragma unroll
            for (int j = 0; j < 4; j++)
                bfr[j] = *(const bf16x8*)&Bs[(wn + j * 16 + m16) * 64 + ((ks * 32 + q * 8) ^ swz)];
            #pragma unroll
            for (int i = 0; i < 4; i++)
                #pragma unroll
                for (int j = 0; j < 4; j++)
                    acc[i][j] = __builtin_amdgcn_mfma_f32_16x16x32_bf16(
                        af[i], bfr[j], acc[i][j], 0, 0, 0);
        }
        __syncthreads();
    }

    // C/D layout: col = lane&15, row = q*4 + reg  [m89-verified]
    #pragma unroll
    for (int i = 0; i < 4; i++)
        #pragma unroll
        for (int j = 0; j < 4; j++)
            #pragma unroll
            for (int r = 0; r < 4; r++) {
                int row = bm + wm + i * 16 + q * 4 + r;
                int col = bn + wn + j * 16 + m16;
                C[(size_t)row * N + col] = acc[i][j][r];
            }
}

// ---------------------------------------------------------------------------
extern "C" void kernel_launch(void* const* d_in, const int* in_sizes, int n_in,
                              void* d_out, int out_size, void* d_ws, size_t ws_size,
                              hipStream_t stream) {
    const float* x    = (const float*)d_in[0];   // [32768][1024]
    const float* pw   = (const float*)d_in[1];   // [64][1024]
    const float* mean = (const float*)d_in[2];   // [64][20]
    const float* emb  = (const float*)d_in[3];   // [1024][1280]
    float* out = (float*)d_out;                  // [32768][1024] fp32

    char* ws = (char*)d_ws;
    u16*   z    = (u16*)(ws);                    // 83,886,080 B
    u16*   wswh = (u16*)(ws + 83886080);         //    131,072 B (lane-major frag images)
    u16*   wswl = (u16*)(ws + 84017152);         //    131,072 B
    u16*   embW = (u16*)(ws + 84148224);         //  2,621,440 B
    // total: 86,769,664 B

    k_norm_w<<<64, 256, 0, stream>>>(pw, wswh, wswl);
    k_cvt<<<(EDIM * FDIM / 4) / 256, 256, 0, stream>>>(emb, embW);
    k_fused<<<M_ROWS / 64, 256, 0, stream>>>(x, wswh, wswl, mean, z);
    k_gemm2<<<dim3(EDIM / 128, M_ROWS / 128), 256, 0, stream>>>(z, embW, out);
}